// Round 5
// baseline (354.156 us; speedup 1.0000x reference)
//
#include <hip/hip_runtime.h>
#include <stdint.h>

#define DIM 768
#define HEADS 12
#define SEQ 196
#define BATCH 64
#define NTOK (BATCH*SEQ)   // 12544
#define QKVLD (3*DIM)      // 2304, row stride of qkv workspace
#define SCALE 0.125f       // 64^-0.5

using short8  = __attribute__((ext_vector_type(8))) short;
using short4v = __attribute__((ext_vector_type(4))) short;
using float4v = __attribute__((ext_vector_type(4))) float;
using ushort4v = __attribute__((ext_vector_type(4))) unsigned short;

static __device__ __forceinline__ unsigned short f2bf(float f) {
  union { float f; unsigned u; } v; v.f = f;
  unsigned u = v.u;
  u += 0x7fffu + ((u >> 16) & 1u);   // RNE
  return (unsigned short)(u >> 16);
}

#if defined(__has_builtin)
#if __has_builtin(__builtin_amdgcn_global_load_lds)
#define HAS_GLL 1
#endif
#endif

// Stage 16B/lane: global (per-lane ptr g) -> LDS (wave-uniform base l, lane*16B apart)
static __device__ __forceinline__ void gll16(const unsigned short* g, unsigned short* l) {
#ifdef HAS_GLL
  __builtin_amdgcn_global_load_lds(
      (const __attribute__((address_space(1))) void*)g,
      (__attribute__((address_space(3))) void*)l, 16, 0, 0);
#else
  const int lane = threadIdx.x & 63;
  *(short8*)(l + lane * 8) = *(const short8*)g;
#endif
}

// raw barrier (no vmcnt drain) with compiler memory-motion fences
static __device__ __forceinline__ void barx() {
  asm volatile("" ::: "memory");
  __builtin_amdgcn_s_barrier();
  asm volatile("" ::: "memory");
}
#define VMW6 asm volatile("s_waitcnt vmcnt(6)" ::: "memory")
#define VMW2 asm volatile("s_waitcnt vmcnt(2)" ::: "memory")
#define VMW0 asm volatile("s_waitcnt vmcnt(0)" ::: "memory")

// ---------------- pre-pass: cast x fp32 -> bf16 ----------------
__global__ __launch_bounds__(256) void cast_x_kernel(const float* __restrict__ in,
                                                     unsigned short* __restrict__ out) {
  int i = blockIdx.x * 256 + threadIdx.x;      // exactly NTOK*DIM/4 threads
  float4 v = ((const float4*)in)[i];
  ushort4v o;
  o.x = f2bf(v.x); o.y = f2bf(v.y); o.z = f2bf(v.z); o.w = f2bf(v.w);
  ((ushort4v*)out)[i] = o;
}

// ---------------- pre-pass: transpose + cast W [R][C] fp32 -> Wt [C][R] bf16 ----------------
__global__ __launch_bounds__(256) void transpose_cast_kernel(const float* __restrict__ in,
                                                             unsigned short* __restrict__ out,
                                                             int R, int C) {
  __shared__ float tile[32][33];
  int c0 = blockIdx.x * 32, r0 = blockIdx.y * 32;
  int tx = threadIdx.x, ty = threadIdx.y;      // (32,8)
  for (int i = 0; i < 32; i += 8)
    tile[ty + i][tx] = in[(size_t)(r0 + ty + i) * C + c0 + tx];
  __syncthreads();
  for (int i = 0; i < 32; i += 8)
    out[(size_t)(c0 + ty + i) * R + r0 + tx] = f2bf(tile[tx][ty + i]);
}

// ---------------- pre-pass: transpose static_a per head: saT[h][m][n] = sa[h][n][m] ----------------
__global__ __launch_bounds__(256) void transpose_sa_kernel(const float* __restrict__ in,
                                                           float* __restrict__ out) {
  __shared__ float tile[32][33];
  const int h = blockIdx.z;
  const int n0 = blockIdx.x * 32, m0 = blockIdx.y * 32;
  const int tx = threadIdx.x, ty = threadIdx.y;   // (32,8)
  const float* inh = in + (size_t)h * SEQ * SEQ;
  float* outh = out + (size_t)h * SEQ * SEQ;
  for (int i = 0; i < 32; i += 8)
    if (n0 + ty + i < SEQ && m0 + tx < SEQ)
      tile[ty + i][tx] = inh[(size_t)(n0 + ty + i) * SEQ + m0 + tx];
  __syncthreads();
  for (int i = 0; i < 32; i += 8)
    if (m0 + ty + i < SEQ && n0 + tx < SEQ)
      outh[(size_t)(m0 + ty + i) * SEQ + n0 + tx] = tile[tx][ty + i];
}

// ---------------- GEMM: C[M][N] = A[M][768] * Bt[N][768]^T ----------------
// TLP design: 256x256 tile, 1024 threads (16 waves, 4Mx4N grid, 64x64/wave,
// acc[4][4] = 64 regs -> ~112 VGPR/wave -> 16 waves resident = 2x the TLP of
// the 8-wave variant). A staged in a 4-slot LDS ring (64KB, gll16, counted
// vmcnt(6): A(t+1) has exactly 6 younger VMEM ops -> in-order retire check).
// B (weights, 1.2-3.5MB) is L2/L3-resident -> loaded per tile straight into
// registers; the compiler inserts exact vmcnt for those uses. Overlap of LDS,
// VMEM and MFMA pipes comes from wave-level parallelism (m114), not from
// intra-wave scheduling (rounds 1-4: lockstep waves never overlapped).
// Swizzle chunk^=(row>>1)&3 on BOTH stage-source and LDS reads (0 conflicts).
// MODE 0: C^T-register formulation (mfma(b,a)), bf16 out row-major [M][2304]
// MODE 1: fp32 out[m][768] + bias[n]
template <int MODE>
__global__ __launch_bounds__(1024) void gemm256_kernel(const unsigned short* __restrict__ A,
                                                       const unsigned short* __restrict__ Bt,
                                                       const float* __restrict__ bias,
                                                       unsigned short* __restrict__ outB,
                                                       float* __restrict__ outF) {
  constexpr int K = 768;
  constexpr int NT = 24;                               // K-tiles of 32
  __shared__ __align__(16) unsigned short Als[4][8192];   // [slot][256 rows][32 cols] = 64KB
  const int tid = threadIdx.x;
  const int wid = tid >> 6, lane = tid & 63;
  const int s = lane & 15, q = lane >> 4;
  const int wrM = wid >> 2, wcN = wid & 3;             // 4x4 wave grid, 64x64 per wave
  const int qx8 = ((q ^ ((s >> 1) & 3)) << 3);         // swizzled 16B slot for frag reads

  // XCD-aware bijective swizzle: contiguous id chunk per XCD; m-major ids ->
  // chunk shares A-panels (L2-resident); B re-fetch ~3.5MB/XCD via L3.
  const int nbx = gridDim.x;
  const int nb = gridDim.x * gridDim.y;
  int id = blockIdx.y * nbx + blockIdx.x;
  {
    int x = id & 7, lid = id >> 3;
    int per = nb >> 3, big = nb & 7;
    id = (x < big) ? x * (per + 1) + lid
                   : big * (per + 1) + (x - big) * per + lid;
  }
  const int m0 = (id / nbx) * 256;
  const int n0 = (id % nbx) * 256;

  float4v acc[4][4];
#pragma unroll
  for (int i = 0; i < 4; i++)
#pragma unroll
    for (int j = 0; j < 4; j++) acc[i][j] = (float4v){0.f, 0.f, 0.f, 0.f};

  // A staging: thread t covers 16B chunk t (row t>>2, chunk t&3). Linear LDS
  // dest (gll requirement); SOURCE chunk pre-permuted by the read involution.
  const int srow = tid >> 2;                             // 0..255
  const int scol8 = (((tid & 3) ^ ((srow >> 1) & 3)) << 3);
  const unsigned short* gA = A + (size_t)(m0 + srow) * K + scol8;
  unsigned short* lA0 = &Als[0][0] + wid * 512;          // wave slice: 1KB

  auto stageA = [&](int t_) {
    gll16(gA + t_ * 32, lA0 + (t_ & 3) * 8192);
  };

  // B fragment base pointers (per lane): row n, cols q*8.. (16B), row stride K
  const unsigned short* bp0 = Bt + (size_t)(n0 + wcN * 64 +  0 + s) * K + q * 8;
  const unsigned short* bp1 = Bt + (size_t)(n0 + wcN * 64 + 16 + s) * K + q * 8;
  const unsigned short* bp2 = Bt + (size_t)(n0 + wcN * 64 + 32 + s) * K + q * 8;
  const unsigned short* bp3 = Bt + (size_t)(n0 + wcN * 64 + 48 + s) * K + q * 8;

  // A-frag LDS offsets (elements), tile-invariant. (row>>1)&3 == (s>>1)&3 here.
  const int oA0 = (wrM * 64 +  0 + s) * 32 + qx8;
  const int oA1 = (wrM * 64 + 16 + s) * 32 + qx8;
  const int oA2 = (wrM * 64 + 32 + s) * 32 + qx8;
  const int oA3 = (wrM * 64 + 48 + s) * 32 + qx8;

  // prologue: stage tiles 0,1,2 (3 glls, ordered); retire tile 0 (2 younger).
  stageA(0); stageA(1); stageA(2);
  VMW2;
  barx();

#define MM(C, AF, BF)                                                              \
  do { if (MODE == 0) C = __builtin_amdgcn_mfma_f32_16x16x32_bf16(BF, AF, C, 0, 0, 0); \
       else           C = __builtin_amdgcn_mfma_f32_16x16x32_bf16(AF, BF, C, 0, 0, 0); } while (0)

#pragma unroll 1
  for (int t = 0; t < NT; ++t) {
    const unsigned short* As = &Als[0][0] + (t & 3) * 8192;
    // B frags from L2 (plain loads; compiler emits exact vmcnt before use)
    short8 b0 = *(const short8*)(bp0 + t * 32);
    short8 b1 = *(const short8*)(bp1 + t * 32);
    short8 b2 = *(const short8*)(bp2 + t * 32);
    short8 b3 = *(const short8*)(bp3 + t * 32);
    // A frags from LDS (compiler emits lgkmcnt before use)
    short8 a0 = *(const short8*)&As[oA0];
    short8 a1 = *(const short8*)&As[oA1];
    short8 a2 = *(const short8*)&As[oA2];
    short8 a3 = *(const short8*)&As[oA3];
    if (t < NT - 3) stageA(t + 3);
    __builtin_amdgcn_s_setprio(1);
    MM(acc[0][0], a0, b0); MM(acc[0][1], a0, b1); MM(acc[0][2], a0, b2); MM(acc[0][3], a0, b3);
    MM(acc[1][0], a1, b0); MM(acc[1][1], a1, b1); MM(acc[1][2], a1, b2); MM(acc[1][3], a1, b3);
    MM(acc[2][0], a2, b0); MM(acc[2][1], a2, b1); MM(acc[2][2], a2, b2); MM(acc[2][3], a2, b3);
    MM(acc[3][0], a3, b0); MM(acc[3][1], a3, b1); MM(acc[3][2], a3, b2); MM(acc[3][3], a3, b3);
    __builtin_amdgcn_s_setprio(0);
    // A(t+1) has <=6 younger VMEM ops (A(t+2),A(t+3),B(t)x4); vmcnt is
    // in-order, so <=6 outstanding  =>  A(t+1) landed. Never 0 mid-loop.
    if (t < NT - 3) { VMW6; } else { VMW0; }
    barx();
  }
#undef MM

  if (MODE == 0) {
    // lane (s,q): acc[mi][nj][r] = C[m0+wrM*64+mi*16+s][n0+wcN*64+nj*16+q*4+r]
#pragma unroll
    for (int mi = 0; mi < 4; ++mi) {
      size_t mrow = (size_t)(m0 + wrM * 64 + mi * 16 + s) * QKVLD;
#pragma unroll
      for (int nj = 0; nj < 4; ++nj) {
        int n = n0 + wcN * 64 + nj * 16 + q * 4;
        ushort4v ov;
        ov.x = f2bf(acc[mi][nj][0]); ov.y = f2bf(acc[mi][nj][1]);
        ov.z = f2bf(acc[mi][nj][2]); ov.w = f2bf(acc[mi][nj][3]);
        *(ushort4v*)&outB[mrow + n] = ov;
      }
    }
  } else {
    // lane (s,q): acc[mi][nj][r] = C[m0+wrM*64+mi*16+q*4+r][n0+wcN*64+nj*16+s]
#pragma unroll
    for (int mi = 0; mi < 4; ++mi) {
      int mbase = m0 + wrM * 64 + mi * 16 + q * 4;
#pragma unroll
      for (int nj = 0; nj < 4; ++nj) {
        int ng = n0 + wcN * 64 + nj * 16 + s;
        float bv = bias[ng];
#pragma unroll
        for (int r = 0; r < 4; ++r)
          outF[(size_t)(mbase + r) * 768 + ng] = acc[mi][nj][r] + bv;
      }
    }
  }
}

// ---------------- attention: one block per (b,h), S^T formulation ----------------
// qkv workspace is [NTOK][2304] row-major. K is staged into LDS once (coalesced
// 128B global reads), XOR-swizzled so the permuted-row fragment reads are
// conflict-free-ish; static_a is pre-transposed so bias loads are lane-coalesced.
__global__ __launch_bounds__(256) void attn_kernel(const unsigned short* __restrict__ qkv,
                                                   const float* __restrict__ saT,
                                                   unsigned short* __restrict__ outA) {
  constexpr int WV = 228;   // stride: 114 dwords == 18 mod 32 -> b64 frag reads conflict-free
  __shared__ __align__(16) unsigned short Kl[196 * 64];  // K rows, chunk-swizzled
  __shared__ __align__(16) unsigned short Vt[64 * WV];   // V^T [d][m], m zero-padded to 224
  const int tid = threadIdx.x, wid = tid >> 6, lane = tid & 63;
  const int s = lane & 15, q = lane >> 4;
  const int bh = blockIdx.x;
  const int b = bh / 12, h = bh % 12;
  const unsigned short* Qb = qkv + (size_t)b * SEQ * QKVLD + h * 64;
  const unsigned short* Kb = Qb + 768;
  const unsigned short* Vb = Qb + 1536;

  // stage K: row r, chunk c (16B); LDS chunk = c ^ gK(r); 8 lanes/row -> 128B coalesced
  {
    const int r0 = tid >> 3, c = tid & 7;
    for (int p = 0; p < 7; ++p) {
      int r = p * 32 + r0;
      if (r < 196) {
        short8 v = *(const short8*)&Kb[(size_t)r * QKVLD + c * 8];
        int gk = ((r >> 3) & 3) ^ ((r & 1) << 2);
        *(short8*)&Kl[r * 64 + ((c ^ gk) << 3)] = v;
      }
    }
  }
  // stage V^T: thread covers m = mb*64 + (tid&63), d = d0..d0+15
  {
    const int ms = tid & 63;
    const int d0 = (tid >> 6) * 16;
    for (int mb = 0; mb < 4; ++mb) {
      int m = mb * 64 + ms;
      if (m < 224) {
        if (m < 196) {
          short8 v0 = *(const short8*)&Vb[(size_t)m * QKVLD + d0];
          short8 v1 = *(const short8*)&Vb[(size_t)m * QKVLD + d0 + 8];
          for (int j = 0; j < 8; j++) Vt[(d0 + j) * WV + m] = (unsigned short)v0[j];
          for (int j = 0; j < 8; j++) Vt[(d0 + 8 + j) * WV + m] = (unsigned short)v1[j];
        } else {
          for (int j = 0; j < 16; j++) Vt[(d0 + j) * WV + m] = 0;
        }
      }
    }
  }
  __syncthreads();

  const int pmbase = (s >> 2) * 8 + (s & 3);   // permuted K-row base for A-frag row s
  const float* saTh = saT + (size_t)h * SEQ * SEQ;

  for (int qt = wid; qt < 13; qt += 4) {
    const int n0 = qt * 16;
    const int nq = n0 + s;
    const int nql = nq > 195 ? 195 : nq;
    short8 qf0 = *(const short8*)&Qb[(size_t)nql * QKVLD + q * 8];
    short8 qf1 = *(const short8*)&Qb[(size_t)nql * QKVLD + 32 + q * 8];

    // S^T tiles: tt = 0..12 (tt = 2t + h4; tile (t=6,h4=1) is entirely m>=196 -> skipped)
    float4v sacc[14];
    for (int tt = 0; tt < 13; tt++) {
      int t = tt >> 1, h4 = tt & 1;
      int m = t * 32 + h4 * 4 + pmbase;
      if (m > 195) m = 195;                       // garbage rows, masked later
      int gk = ((m >> 3) & 3) ^ ((m & 1) << 2);
      short8 kf0 = *(const short8*)&Kl[m * 64 + ((q ^ gk) << 3)];
      short8 kf1 = *(const short8*)&Kl[m * 64 + (((4 + q) ^ gk) << 3)];
      float4v z = (float4v){0.f, 0.f, 0.f, 0.f};
      z = __builtin_amdgcn_mfma_f32_16x16x32_bf16(kf0, qf0, z, 0, 0, 0);
      z = __builtin_amdgcn_mfma_f32_16x16x32_bf16(kf1, qf1, z, 0, 0, 0);
      sacc[tt] = z;
    }
    sacc[13] = (float4v){0.f, 0.f, 0.f, 0.f};

    // column softmax: lane owns column n. Valid m: tt<12 all; tt==12 only q==0.
    float mx = -3.0e38f;
    for (int tt = 0; tt < 12; tt++)
      for (int i = 0; i < 4; i++) mx = fmaxf(mx, sacc[tt][i]);
    if (q == 0)
      for (int i = 0; i < 4; i++) mx = fmaxf(mx, sacc[12][i]);
    mx = fmaxf(mx, __shfl_xor(mx, 16));
    mx = fmaxf(mx, __shfl_xor(mx, 32));
    const float CE = SCALE * 1.44269504f;
    float sm = 0.f;
    for (int tt = 0; tt < 12; tt++)
      for (int i = 0; i < 4; i++) {
        float e = __builtin_amdgcn_exp2f((sacc[tt][i] - mx) * CE);
        sacc[tt][i] = e; sm += e;
      }
    if (q == 0) {
      for (int i = 0; i < 4; i++) {
        float e = __builtin_amdgcn_exp2f((sacc[12][i] - mx) * CE);
        sacc[12][i] = e; sm += e;
      }
    } else {
      sacc[12] = (float4v){0.f, 0.f, 0.f, 0.f};
    }
    sm += __shfl_xor(sm, 16);
    sm += __shfl_xor(sm, 32);
    const float inv = 1.0f / sm;

    // P^T fragments: pfrag[t][j] = P^T[m = t*32 + q*8 + j][n], j = h4*4 + i
    // bias from saT[m][n]: scalar f32 loads, 16 lanes hit 16 consecutive n (coalesced)
    short8 pfrag[7];
    for (int t = 0; t < 7; t++) {
      short8 pf;
      for (int h4 = 0; h4 < 2; h4++) {
        int tt = 2 * t + h4;
        bool valid = (tt < 12) || (tt == 12 && q == 0);
        float a0 = 0.f, a1 = 0.f, a2 = 0.f, a3 = 0.f;
        if (valid) {
          const float* sp = saTh + (size_t)(t * 32 + q * 8 + h4 * 4) * SEQ + nql;
          a0 = sp[0]; a1 = sp[SEQ]; a2 = sp[2 * SEQ]; a3 = sp[3 * SEQ];
        }
        int src = valid ? tt : 13;
        float pv0 = valid ? (sacc[src][0] * inv + a0) : 0.f;
        float pv1 = valid ? (sacc[src][1] * inv + a1) : 0.f;
        float pv2 = valid ? (sacc[src][2] * inv + a2) : 0.f;
        float pv3 = valid ? (sacc[src][3] * inv + a3) : 0.f;
        pf[h4 * 4 + 0] = (short)f2bf(pv0);
        pf[h4 * 4 + 1] = (short)f2bf(pv1);
        pf[h4 * 4 + 2] = (short)f2bf(pv2);
        pf[h4 * 4 + 3] = (short)f2bf(pv3);
      }
      pfrag[t] = pf;
    }

    // O^T = V^T . P^T : A-frag = V^T rows (from LDS, two b64 reads), B-frag = pfrag
    for (int dt = 0; dt < 4; dt++) {
      float4v o = (float4v){0.f, 0.f, 0.f, 0.f};
      for (int t = 0; t < 7; t++) {
        const unsigned short* vp = &Vt[(dt * 16 + s) * WV + t * 32 + q * 8];
        short4v v0 = *(const short4v*)vp;
        short4v v1 = *(const short4v*)(vp + 4);
        short8 vf;
        vf[0] = v0[0]; vf[1] = v0[1]; vf[2] = v0[2]; vf[3] = v0[3];
        vf[4] = v1[0]; vf[5] = v1[1]; vf[6] = v1[2]; vf[7] = v1[3];
        o = __builtin_amdgcn_mfma_f32_16x16x32_bf16(vf, pfrag[t], o, 0, 0, 0);
      }
      // lane holds O^T[d = dt*16 + q*4 + r][n = nq]
      if (nq < 196) {
        ushort4v ov;
        ov.x = f2bf(o[0]); ov.y = f2bf(o[1]); ov.z = f2bf(o[2]); ov.w = f2bf(o[3]);
        *(ushort4v*)&outA[((size_t)b * SEQ + nq) * DIM + h * 64 + dt * 16 + q * 4] = ov;
      }
    }
  }
}

extern "C" void kernel_launch(void* const* d_in, const int* in_sizes, int n_in,
                              void* d_out, int out_size, void* d_ws, size_t ws_size,
                              hipStream_t stream) {
  const float* x        = (const float*)d_in[0];
  const float* Wqkv     = (const float*)d_in[1];
  const float* static_a = (const float*)d_in[2];
  const float* Wproj    = (const float*)d_in[3];
  const float* bproj    = (const float*)d_in[4];
  float* out = (float*)d_out;

  unsigned char* ws = (unsigned char*)d_ws;
  size_t off = 0;
  unsigned short* qkv_ws = (unsigned short*)(ws + off); off += (size_t)NTOK * QKVLD * 2;   // 57.8 MB
  unsigned short* xa_ws  = (unsigned short*)(ws + off); off += (size_t)NTOK * DIM * 2;     // x_bf16, reused as attn-out
  unsigned short* wqkvt  = (unsigned short*)(ws + off); off += (size_t)3 * DIM * DIM * 2;  // W_qkv^T bf16
  unsigned short* wprojt = (unsigned short*)(ws + off); off += (size_t)DIM * DIM * 2;      // W_proj^T bf16
  float* saT_ws          = (float*)(ws + off);          off += (size_t)HEADS * SEQ * SEQ * 4; // 1.84 MB

  cast_x_kernel<<<NTOK * DIM / 4 / 256, 256, 0, stream>>>(x, xa_ws);
  transpose_cast_kernel<<<dim3(3 * DIM / 32, DIM / 32), dim3(32, 8), 0, stream>>>(Wqkv, wqkvt, DIM, 3 * DIM);
  transpose_cast_kernel<<<dim3(DIM / 32, DIM / 32), dim3(32, 8), 0, stream>>>(Wproj, wprojt, DIM, DIM);
  transpose_sa_kernel<<<dim3(7, 7, HEADS), dim3(32, 8), 0, stream>>>(static_a, saT_ws);
  gemm256_kernel<0><<<dim3(3 * DIM / 256, NTOK / 256), 1024, 0, stream>>>(xa_ws, wqkvt, nullptr, qkv_ws, nullptr);
  attn_kernel<<<BATCH * HEADS, 256, 0, stream>>>(qkv_ws, saT_ws, xa_ws);
  gemm256_kernel<1><<<dim3(DIM / 256, NTOK / 256), 1024, 0, stream>>>(xa_ws, wprojt, bproj, nullptr, out);
}

// Round 6
// 242.894 us; speedup vs baseline: 1.4581x; 1.4581x over previous
//
#include <hip/hip_runtime.h>
#include <stdint.h>

#define DIM 768
#define HEADS 12
#define SEQ 196
#define BATCH 64
#define NTOK (BATCH*SEQ)   // 12544
#define QKVLD (3*DIM)      // 2304, row stride of qkv workspace
#define SCALE 0.125f       // 64^-0.5

using short8  = __attribute__((ext_vector_type(8))) short;
using short4v = __attribute__((ext_vector_type(4))) short;
using float4v = __attribute__((ext_vector_type(4))) float;
using ushort4v = __attribute__((ext_vector_type(4))) unsigned short;

static __device__ __forceinline__ unsigned short f2bf(float f) {
  union { float f; unsigned u; } v; v.f = f;
  unsigned u = v.u;
  u += 0x7fffu + ((u >> 16) & 1u);   // RNE
  return (unsigned short)(u >> 16);
}

#if defined(__has_builtin)
#if __has_builtin(__builtin_amdgcn_global_load_lds)
#define HAS_GLL 1
#endif
#endif

// Stage 16B/lane: global (per-lane ptr g) -> LDS (wave-uniform base l, lane*16B apart)
static __device__ __forceinline__ void gll16(const unsigned short* g, unsigned short* l) {
#ifdef HAS_GLL
  __builtin_amdgcn_global_load_lds(
      (const __attribute__((address_space(1))) void*)g,
      (__attribute__((address_space(3))) void*)l, 16, 0, 0);
#else
  const int lane = threadIdx.x & 63;
  *(short8*)(l + lane * 8) = *(const short8*)g;
#endif
}

// raw barrier with compiler memory-motion fences
static __device__ __forceinline__ void barx() {
  asm volatile("" ::: "memory");
  __builtin_amdgcn_s_barrier();
  asm volatile("" ::: "memory");
}
#define VMW0 asm volatile("s_waitcnt vmcnt(0)" ::: "memory")

// ---------------- fused pre-pass: cast_x | Wqkv^T | Wproj^T | saT ----------------
// One launch instead of four (inter-kernel gaps were ~30-45us of the budget).
// Flat grid of 256-thread blocks partitioned by range:
//   [0, 9408)                cast x fp32->bf16 (vectorized float4 -> ushort4)
//   [9408, 9408+1728)        transpose+cast W_qkv [768][2304] -> [2304][768]
//   [+1728, +1728+576)       transpose+cast W_proj [768][768] -> [768][768]
//   [+576, +576+588)         transpose static_a per head: saT[h][m][n]=sa[h][n][m]
#define PREP_NB0 9408
#define PREP_NB1 1728
#define PREP_NB2 576
#define PREP_NB3 588
#define PREP_NB (PREP_NB0+PREP_NB1+PREP_NB2+PREP_NB3)

__global__ __launch_bounds__(256) void prep_kernel(const float* __restrict__ x,
                                                   const float* __restrict__ Wqkv,
                                                   const float* __restrict__ Wproj,
                                                   const float* __restrict__ sa,
                                                   unsigned short* __restrict__ x_bf,
                                                   unsigned short* __restrict__ wqkvt,
                                                   unsigned short* __restrict__ wprojt,
                                                   float* __restrict__ saT) {
  __shared__ float tile[32][33];
  const int bid = blockIdx.x;
  const int tid = threadIdx.x;
  if (bid < PREP_NB0) {
    int i = bid * 256 + tid;
    float4 v = ((const float4*)x)[i];
    ushort4v o;
    o.x = f2bf(v.x); o.y = f2bf(v.y); o.z = f2bf(v.z); o.w = f2bf(v.w);
    ((ushort4v*)x_bf)[i] = o;
    return;
  }
  const int tx = tid & 31, ty = tid >> 5;    // (32,8)
  if (bid < PREP_NB0 + PREP_NB1) {
    int lb = bid - PREP_NB0;
    int c0 = (lb % 72) * 32, r0 = (lb / 72) * 32;   // C=2304, R=768
    for (int i = 0; i < 32; i += 8)
      tile[ty + i][tx] = Wqkv[(size_t)(r0 + ty + i) * 2304 + c0 + tx];
    __syncthreads();
    for (int i = 0; i < 32; i += 8)
      wqkvt[(size_t)(c0 + ty + i) * 768 + r0 + tx] = f2bf(tile[tx][ty + i]);
    return;
  }
  if (bid < PREP_NB0 + PREP_NB1 + PREP_NB2) {
    int lb = bid - PREP_NB0 - PREP_NB1;
    int c0 = (lb % 24) * 32, r0 = (lb / 24) * 32;   // C=R=768
    for (int i = 0; i < 32; i += 8)
      tile[ty + i][tx] = Wproj[(size_t)(r0 + ty + i) * 768 + c0 + tx];
    __syncthreads();
    for (int i = 0; i < 32; i += 8)
      wprojt[(size_t)(c0 + ty + i) * 768 + r0 + tx] = f2bf(tile[tx][ty + i]);
    return;
  }
  {
    int lb = bid - PREP_NB0 - PREP_NB1 - PREP_NB2;
    int n0 = (lb % 7) * 32; int rest = lb / 7;
    int m0 = (rest % 7) * 32; int h = rest / 7;
    const float* inh = sa + (size_t)h * SEQ * SEQ;
    float* outh = saT + (size_t)h * SEQ * SEQ;
    for (int i = 0; i < 32; i += 8)
      if (n0 + ty + i < SEQ && m0 + tx < SEQ)
        tile[ty + i][tx] = inh[(size_t)(n0 + ty + i) * SEQ + m0 + tx];
    __syncthreads();
    for (int i = 0; i < 32; i += 8)
      if (m0 + ty + i < SEQ && n0 + tx < SEQ)
        outh[(size_t)(m0 + ty + i) * SEQ + n0 + tx] = tile[tx][ty + i];
  }
}

// ---------------- GEMM: C[M][N] = A[M][768] * Bt[N][768]^T ----------------
// TLP design (m97 recipe): 128x256 tile, BK=32, 512 threads (8 waves 2Mx4N,
// 64x64/wave, acc[4][4]=64 regs). __launch_bounds__(512,4) caps VGPR at 128 ->
// 2 blocks/CU co-resident (LDS 48KB: 2-slot ring). Simple per-tile schedule:
//   { stage(t+1) -> frag reads(t) -> 16 MFMA -> vmcnt(0) -> barrier }
// The vmcnt(0) drain stalls THIS block, but the co-resident block fills the
// pipes (m114 wave-level overlap; m97's 874TF works exactly this way). Per-wave
// LDS reads drop 12->8 b128/tile vs the 256^2 shape.
// Swizzle chunk^=(row>>1)&3 on BOTH stage-source and frag reads (0 conflicts,
// verified r2/r3).
// MODE 0: C^T-register formulation (mfma(b,a)), bf16 out row-major [M][2304]
// MODE 1: fp32 out[m][768] + bias[n]
template <int MODE>
__global__ __launch_bounds__(512, 4) void gemm_kernel(const unsigned short* __restrict__ A,
                                                      const unsigned short* __restrict__ Bt,
                                                      const float* __restrict__ bias,
                                                      unsigned short* __restrict__ outB,
                                                      float* __restrict__ outF) {
  constexpr int K = 768;
  constexpr int NT = 24;                               // K-tiles of 32
  __shared__ __align__(16) unsigned short Als[2][4096];   // [slot][128 rows][32 cols] = 16KB
  __shared__ __align__(16) unsigned short Bls[2][8192];   // [slot][256 rows][32 cols] = 32KB
  const int tid = threadIdx.x;
  const int wid = tid >> 6, lane = tid & 63;
  const int s = lane & 15, q = lane >> 4;
  const int wrM = wid >> 2, wcN = wid & 3;             // 2x4 wave grid, 64x64 per wave
  const int qx8 = ((q ^ ((s >> 1) & 3)) << 3);         // swizzled 16B slot for frag reads

  // XCD-aware bijective swizzle: contiguous id chunk per XCD -> L2 locality.
  const int nbx = gridDim.x;
  const int nb = gridDim.x * gridDim.y;
  int id = blockIdx.y * nbx + blockIdx.x;
  {
    int x = id & 7, lid = id >> 3;
    int per = nb >> 3, big = nb & 7;
    id = (x < big) ? x * (per + 1) + lid
                   : big * (per + 1) + (x - big) * per + lid;
  }
  const int m0 = (id / nbx) * 128;
  const int n0 = (id % nbx) * 256;

  float4v acc[4][4];
#pragma unroll
  for (int i = 0; i < 4; i++)
#pragma unroll
    for (int j = 0; j < 4; j++) acc[i][j] = (float4v){0.f, 0.f, 0.f, 0.f};

  // Staging: thread t covers 16B chunk (row=t>>2, chunk=t&3). A: 128 rows = 1
  // gll; B: 256 rows = 2 glls. Linear LDS dest (gll requirement); SOURCE chunk
  // pre-permuted by the read involution. (srow+128)>>1 keeps the same &3.
  const int srow = tid >> 2;                             // 0..127
  const int scol8 = (((tid & 3) ^ ((srow >> 1) & 3)) << 3);
  const unsigned short* gA = A + (size_t)(m0 + srow) * K + scol8;
  const unsigned short* gB = Bt + (size_t)(n0 + srow) * K + scol8;

  auto stage = [&](int t_) {
    const int sl = t_ & 1;
    gll16(gA + t_ * 32, &Als[sl][0] + wid * 512);
    gll16(gB + t_ * 32, &Bls[sl][0] + wid * 512);
    gll16(gB + t_ * 32 + 128 * K, &Bls[sl][0] + wid * 512 + 4096);
  };

  // A-frag rows (within 128) and B-frag rows (within 256); bases are x16 so
  // (row>>1)&3 == (s>>1)&3 -> qx8 valid for all.
  const int oA0 = (wrM * 64 +  0 + s) * 32 + qx8;
  const int oA1 = (wrM * 64 + 16 + s) * 32 + qx8;
  const int oA2 = (wrM * 64 + 32 + s) * 32 + qx8;
  const int oA3 = (wrM * 64 + 48 + s) * 32 + qx8;
  const int oB0 = (wcN * 64 +  0 + s) * 32 + qx8;
  const int oB1 = (wcN * 64 + 16 + s) * 32 + qx8;
  const int oB2 = (wcN * 64 + 32 + s) * 32 + qx8;
  const int oB3 = (wcN * 64 + 48 + s) * 32 + qx8;

  stage(0);
  VMW0;
  barx();

#define MM(C, AF, BF)                                                              \
  do { if (MODE == 0) C = __builtin_amdgcn_mfma_f32_16x16x32_bf16(BF, AF, C, 0, 0, 0); \
       else           C = __builtin_amdgcn_mfma_f32_16x16x32_bf16(AF, BF, C, 0, 0, 0); } while (0)

#pragma unroll 1
  for (int t = 0; t < NT; ++t) {
    const unsigned short* As = &Als[t & 1][0];
    const unsigned short* Bs = &Bls[t & 1][0];
    if (t < NT - 1) stage(t + 1);          // into the other slot (WAR-safe: its
                                           // readers finished before last barrier)
    short8 a0 = *(const short8*)&As[oA0];
    short8 a1 = *(const short8*)&As[oA1];
    short8 a2 = *(const short8*)&As[oA2];
    short8 a3 = *(const short8*)&As[oA3];
    short8 b0 = *(const short8*)&Bs[oB0];
    short8 b1 = *(const short8*)&Bs[oB1];
    short8 b2 = *(const short8*)&Bs[oB2];
    short8 b3 = *(const short8*)&Bs[oB3];
    __builtin_amdgcn_s_setprio(1);
    MM(acc[0][0], a0, b0); MM(acc[0][1], a0, b1); MM(acc[0][2], a0, b2); MM(acc[0][3], a0, b3);
    MM(acc[1][0], a1, b0); MM(acc[1][1], a1, b1); MM(acc[1][2], a1, b2); MM(acc[1][3], a1, b3);
    MM(acc[2][0], a2, b0); MM(acc[2][1], a2, b1); MM(acc[2][2], a2, b2); MM(acc[2][3], a2, b3);
    MM(acc[3][0], a3, b0); MM(acc[3][1], a3, b1); MM(acc[3][2], a3, b2); MM(acc[3][3], a3, b3);
    __builtin_amdgcn_s_setprio(0);
    VMW0;            // next tile landed; drain overlapped by co-resident block
    barx();
  }
#undef MM

  if (MODE == 0) {
    // lane (s,q): acc[mi][nj][r] = C[m0+wrM*64+mi*16+s][n0+wcN*64+nj*16+q*4+r]
#pragma unroll
    for (int mi = 0; mi < 4; ++mi) {
      size_t mrow = (size_t)(m0 + wrM * 64 + mi * 16 + s) * QKVLD;
#pragma unroll
      for (int nj = 0; nj < 4; ++nj) {
        int n = n0 + wcN * 64 + nj * 16 + q * 4;
        ushort4v ov;
        ov.x = f2bf(acc[mi][nj][0]); ov.y = f2bf(acc[mi][nj][1]);
        ov.z = f2bf(acc[mi][nj][2]); ov.w = f2bf(acc[mi][nj][3]);
        *(ushort4v*)&outB[mrow + n] = ov;
      }
    }
  } else {
    // lane (s,q): acc[mi][nj][r] = C[m0+wrM*64+mi*16+q*4+r][n0+wcN*64+nj*16+s]
#pragma unroll
    for (int mi = 0; mi < 4; ++mi) {
      int mbase = m0 + wrM * 64 + mi * 16 + q * 4;
#pragma unroll
      for (int nj = 0; nj < 4; ++nj) {
        int ng = n0 + wcN * 64 + nj * 16 + s;
        float bv = bias[ng];
#pragma unroll
        for (int r = 0; r < 4; ++r)
          outF[(size_t)(mbase + r) * 768 + ng] = acc[mi][nj][r] + bv;
      }
    }
  }
}

// ---------------- attention: one block per (b,h), S^T formulation ----------------
// qkv workspace is [NTOK][2304] row-major. K staged in LDS (coalesced, XOR-
// swizzled); V^T staged for PV; static_a pre-transposed -> coalesced bias loads.
__global__ __launch_bounds__(256) void attn_kernel(const unsigned short* __restrict__ qkv,
                                                   const float* __restrict__ saT,
                                                   unsigned short* __restrict__ outA) {
  constexpr int WV = 228;   // stride: 114 dwords == 18 mod 32 -> b64 frag reads conflict-free
  __shared__ __align__(16) unsigned short Kl[196 * 64];  // K rows, chunk-swizzled
  __shared__ __align__(16) unsigned short Vt[64 * WV];   // V^T [d][m], m zero-padded to 224
  const int tid = threadIdx.x, wid = tid >> 6, lane = tid & 63;
  const int s = lane & 15, q = lane >> 4;
  const int bh = blockIdx.x;
  const int b = bh / 12, h = bh % 12;
  const unsigned short* Qb = qkv + (size_t)b * SEQ * QKVLD + h * 64;
  const unsigned short* Kb = Qb + 768;
  const unsigned short* Vb = Qb + 1536;

  // stage K: row r, chunk c (16B); LDS chunk = c ^ gK(r); 8 lanes/row -> 128B coalesced
  {
    const int r0 = tid >> 3, c = tid & 7;
    for (int p = 0; p < 7; ++p) {
      int r = p * 32 + r0;
      if (r < 196) {
        short8 v = *(const short8*)&Kb[(size_t)r * QKVLD + c * 8];
        int gk = ((r >> 3) & 3) ^ ((r & 1) << 2);
        *(short8*)&Kl[r * 64 + ((c ^ gk) << 3)] = v;
      }
    }
  }
  // stage V^T: thread covers m = mb*64 + (tid&63), d = d0..d0+15
  {
    const int ms = tid & 63;
    const int d0 = (tid >> 6) * 16;
    for (int mb = 0; mb < 4; ++mb) {
      int m = mb * 64 + ms;
      if (m < 224) {
        if (m < 196) {
          short8 v0 = *(const short8*)&Vb[(size_t)m * QKVLD + d0];
          short8 v1 = *(const short8*)&Vb[(size_t)m * QKVLD + d0 + 8];
          for (int j = 0; j < 8; j++) Vt[(d0 + j) * WV + m] = (unsigned short)v0[j];
          for (int j = 0; j < 8; j++) Vt[(d0 + 8 + j) * WV + m] = (unsigned short)v1[j];
        } else {
          for (int j = 0; j < 16; j++) Vt[(d0 + j) * WV + m] = 0;
        }
      }
    }
  }
  __syncthreads();

  const int pmbase = (s >> 2) * 8 + (s & 3);   // permuted K-row base for A-frag row s
  const float* saTh = saT + (size_t)h * SEQ * SEQ;

  for (int qt = wid; qt < 13; qt += 4) {
    const int n0 = qt * 16;
    const int nq = n0 + s;
    const int nql = nq > 195 ? 195 : nq;
    short8 qf0 = *(const short8*)&Qb[(size_t)nql * QKVLD + q * 8];
    short8 qf1 = *(const short8*)&Qb[(size_t)nql * QKVLD + 32 + q * 8];

    // S^T tiles: tt = 0..12 (tt = 2t + h4; tile (t=6,h4=1) is entirely m>=196 -> skipped)
    float4v sacc[14];
    for (int tt = 0; tt < 13; tt++) {
      int t = tt >> 1, h4 = tt & 1;
      int m = t * 32 + h4 * 4 + pmbase;
      if (m > 195) m = 195;                       // garbage rows, masked later
      int gk = ((m >> 3) & 3) ^ ((m & 1) << 2);
      short8 kf0 = *(const short8*)&Kl[m * 64 + ((q ^ gk) << 3)];
      short8 kf1 = *(const short8*)&Kl[m * 64 + (((4 + q) ^ gk) << 3)];
      float4v z = (float4v){0.f, 0.f, 0.f, 0.f};
      z = __builtin_amdgcn_mfma_f32_16x16x32_bf16(kf0, qf0, z, 0, 0, 0);
      z = __builtin_amdgcn_mfma_f32_16x16x32_bf16(kf1, qf1, z, 0, 0, 0);
      sacc[tt] = z;
    }
    sacc[13] = (float4v){0.f, 0.f, 0.f, 0.f};

    // column softmax: lane owns column n. Valid m: tt<12 all; tt==12 only q==0.
    float mx = -3.0e38f;
    for (int tt = 0; tt < 12; tt++)
      for (int i = 0; i < 4; i++) mx = fmaxf(mx, sacc[tt][i]);
    if (q == 0)
      for (int i = 0; i < 4; i++) mx = fmaxf(mx, sacc[12][i]);
    mx = fmaxf(mx, __shfl_xor(mx, 16));
    mx = fmaxf(mx, __shfl_xor(mx, 32));
    const float CE = SCALE * 1.44269504f;
    float sm = 0.f;
    for (int tt = 0; tt < 12; tt++)
      for (int i = 0; i < 4; i++) {
        float e = __builtin_amdgcn_exp2f((sacc[tt][i] - mx) * CE);
        sacc[tt][i] = e; sm += e;
      }
    if (q == 0) {
      for (int i = 0; i < 4; i++) {
        float e = __builtin_amdgcn_exp2f((sacc[12][i] - mx) * CE);
        sacc[12][i] = e; sm += e;
      }
    } else {
      sacc[12] = (float4v){0.f, 0.f, 0.f, 0.f};
    }
    sm += __shfl_xor(sm, 16);
    sm += __shfl_xor(sm, 32);
    const float inv = 1.0f / sm;

    // P^T fragments: pfrag[t][j] = P^T[m = t*32 + q*8 + j][n], j = h4*4 + i
    // bias from saT[m][n]: scalar f32 loads, 16 lanes hit 16 consecutive n (coalesced)
    short8 pfrag[7];
    for (int t = 0; t < 7; t++) {
      short8 pf;
      for (int h4 = 0; h4 < 2; h4++) {
        int tt = 2 * t + h4;
        bool valid = (tt < 12) || (tt == 12 && q == 0);
        float a0 = 0.f, a1 = 0.f, a2 = 0.f, a3 = 0.f;
        if (valid) {
          const float* sp = saTh + (size_t)(t * 32 + q * 8 + h4 * 4) * SEQ + nql;
          a0 = sp[0]; a1 = sp[SEQ]; a2 = sp[2 * SEQ]; a3 = sp[3 * SEQ];
        }
        int src = valid ? tt : 13;
        float pv0 = valid ? (sacc[src][0] * inv + a0) : 0.f;
        float pv1 = valid ? (sacc[src][1] * inv + a1) : 0.f;
        float pv2 = valid ? (sacc[src][2] * inv + a2) : 0.f;
        float pv3 = valid ? (sacc[src][3] * inv + a3) : 0.f;
        pf[h4 * 4 + 0] = (short)f2bf(pv0);
        pf[h4 * 4 + 1] = (short)f2bf(pv1);
        pf[h4 * 4 + 2] = (short)f2bf(pv2);
        pf[h4 * 4 + 3] = (short)f2bf(pv3);
      }
      pfrag[t] = pf;
    }

    // O^T = V^T . P^T : A-frag = V^T rows (from LDS, two b64 reads), B-frag = pfrag
    for (int dt = 0; dt < 4; dt++) {
      float4v o = (float4v){0.f, 0.f, 0.f, 0.f};
      for (int t = 0; t < 7; t++) {
        const unsigned short* vp = &Vt[(dt * 16 + s) * WV + t * 32 + q * 8];
        short4v v0 = *(const short4v*)vp;
        short4v v1 = *(const short4v*)(vp + 4);
        short8 vf;
        vf[0] = v0[0]; vf[1] = v0[1]; vf[2] = v0[2]; vf[3] = v0[3];
        vf[4] = v1[0]; vf[5] = v1[1]; vf[6] = v1[2]; vf[7] = v1[3];
        o = __builtin_amdgcn_mfma_f32_16x16x32_bf16(vf, pfrag[t], o, 0, 0, 0);
      }
      // lane holds O^T[d = dt*16 + q*4 + r][n = nq]
      if (nq < 196) {
        ushort4v ov;
        ov.x = f2bf(o[0]); ov.y = f2bf(o[1]); ov.z = f2bf(o[2]); ov.w = f2bf(o[3]);
        *(ushort4v*)&outA[((size_t)b * SEQ + nq) * DIM + h * 64 + dt * 16 + q * 4] = ov;
      }
    }
  }
}

extern "C" void kernel_launch(void* const* d_in, const int* in_sizes, int n_in,
                              void* d_out, int out_size, void* d_ws, size_t ws_size,
                              hipStream_t stream) {
  const float* x        = (const float*)d_in[0];
  const float* Wqkv     = (const float*)d_in[1];
  const float* static_a = (const float*)d_in[2];
  const float* Wproj    = (const float*)d_in[3];
  const float* bproj    = (const float*)d_in[4];
  float* out = (float*)d_out;

  unsigned char* ws = (unsigned char*)d_ws;
  size_t off = 0;
  unsigned short* qkv_ws = (unsigned short*)(ws + off); off += (size_t)NTOK * QKVLD * 2;   // 57.8 MB
  unsigned short* xa_ws  = (unsigned short*)(ws + off); off += (size_t)NTOK * DIM * 2;     // x_bf16, reused as attn-out
  unsigned short* wqkvt  = (unsigned short*)(ws + off); off += (size_t)3 * DIM * DIM * 2;  // W_qkv^T bf16
  unsigned short* wprojt = (unsigned short*)(ws + off); off += (size_t)DIM * DIM * 2;      // W_proj^T bf16
  float* saT_ws          = (float*)(ws + off);          off += (size_t)HEADS * SEQ * SEQ * 4; // 1.84 MB

  prep_kernel<<<PREP_NB, 256, 0, stream>>>(x, Wqkv, Wproj, static_a,
                                           xa_ws, wqkvt, wprojt, saT_ws);
  gemm_kernel<0><<<dim3(3 * DIM / 256, NTOK / 128), 512, 0, stream>>>(xa_ws, wqkvt, nullptr, qkv_ws, nullptr);
  attn_kernel<<<BATCH * HEADS, 256, 0, stream>>>(qkv_ws, saT_ws, xa_ws);
  gemm_kernel<1><<<dim3(DIM / 256, NTOK / 128), 512, 0, stream>>>(xa_ws, wprojt, bproj, nullptr, out);
}

// Round 7
// 228.631 us; speedup vs baseline: 1.5490x; 1.0624x over previous
//
#include <hip/hip_runtime.h>
#include <stdint.h>

#define DIM 768
#define HEADS 12
#define SEQ 196
#define BATCH 64
#define NTOK (BATCH*SEQ)   // 12544
#define QKVLD (3*DIM)      // 2304, row stride of qkv workspace
#define SCALE 0.125f       // 64^-0.5

using short8  = __attribute__((ext_vector_type(8))) short;
using short4v = __attribute__((ext_vector_type(4))) short;
using float4v = __attribute__((ext_vector_type(4))) float;
using ushort4v = __attribute__((ext_vector_type(4))) unsigned short;

static __device__ __forceinline__ unsigned short f2bf(float f) {
  union { float f; unsigned u; } v; v.f = f;
  unsigned u = v.u;
  u += 0x7fffu + ((u >> 16) & 1u);   // RNE
  return (unsigned short)(u >> 16);
}

#if defined(__has_builtin)
#if __has_builtin(__builtin_amdgcn_global_load_lds)
#define HAS_GLL 1
#endif
#endif

// Stage 16B/lane: global (per-lane ptr g) -> LDS (wave-uniform base l, lane*16B apart)
static __device__ __forceinline__ void gll16(const unsigned short* g, unsigned short* l) {
#ifdef HAS_GLL
  __builtin_amdgcn_global_load_lds(
      (const __attribute__((address_space(1))) void*)g,
      (__attribute__((address_space(3))) void*)l, 16, 0, 0);
#else
  const int lane = threadIdx.x & 63;
  *(short8*)(l + lane * 8) = *(const short8*)g;
#endif
}

// raw barrier (no vmcnt drain) with compiler memory-motion fences
static __device__ __forceinline__ void barx() {
  asm volatile("" ::: "memory");
  __builtin_amdgcn_s_barrier();
  asm volatile("" ::: "memory");
}
#define VMW8 asm volatile("s_waitcnt vmcnt(8)" ::: "memory")
#define VMW4 asm volatile("s_waitcnt vmcnt(4)" ::: "memory")
#define VMW0 asm volatile("s_waitcnt vmcnt(0)" ::: "memory")

// ---------------- fused pre-pass: cast_x | Wqkv^T | Wproj^T | saT ----------------
#define PREP_NB0 9408
#define PREP_NB1 1728
#define PREP_NB2 576
#define PREP_NB3 588
#define PREP_NB (PREP_NB0+PREP_NB1+PREP_NB2+PREP_NB3)

__global__ __launch_bounds__(256) void prep_kernel(const float* __restrict__ x,
                                                   const float* __restrict__ Wqkv,
                                                   const float* __restrict__ Wproj,
                                                   const float* __restrict__ sa,
                                                   unsigned short* __restrict__ x_bf,
                                                   unsigned short* __restrict__ wqkvt,
                                                   unsigned short* __restrict__ wprojt,
                                                   float* __restrict__ saT) {
  __shared__ float tile[32][33];
  const int bid = blockIdx.x;
  const int tid = threadIdx.x;
  if (bid < PREP_NB0) {
    int i = bid * 256 + tid;
    float4 v = ((const float4*)x)[i];
    ushort4v o;
    o.x = f2bf(v.x); o.y = f2bf(v.y); o.z = f2bf(v.z); o.w = f2bf(v.w);
    ((ushort4v*)x_bf)[i] = o;
    return;
  }
  const int tx = tid & 31, ty = tid >> 5;    // (32,8)
  if (bid < PREP_NB0 + PREP_NB1) {
    int lb = bid - PREP_NB0;
    int c0 = (lb % 72) * 32, r0 = (lb / 72) * 32;   // C=2304, R=768
    for (int i = 0; i < 32; i += 8)
      tile[ty + i][tx] = Wqkv[(size_t)(r0 + ty + i) * 2304 + c0 + tx];
    __syncthreads();
    for (int i = 0; i < 32; i += 8)
      wqkvt[(size_t)(c0 + ty + i) * 768 + r0 + tx] = f2bf(tile[tx][ty + i]);
    return;
  }
  if (bid < PREP_NB0 + PREP_NB1 + PREP_NB2) {
    int lb = bid - PREP_NB0 - PREP_NB1;
    int c0 = (lb % 24) * 32, r0 = (lb / 24) * 32;   // C=R=768
    for (int i = 0; i < 32; i += 8)
      tile[ty + i][tx] = Wproj[(size_t)(r0 + ty + i) * 768 + c0 + tx];
    __syncthreads();
    for (int i = 0; i < 32; i += 8)
      wprojt[(size_t)(c0 + ty + i) * 768 + r0 + tx] = f2bf(tile[tx][ty + i]);
    return;
  }
  {
    int lb = bid - PREP_NB0 - PREP_NB1 - PREP_NB2;
    int n0 = (lb % 7) * 32; int rest = lb / 7;
    int m0 = (rest % 7) * 32; int h = rest / 7;
    const float* inh = sa + (size_t)h * SEQ * SEQ;
    float* outh = saT + (size_t)h * SEQ * SEQ;
    for (int i = 0; i < 32; i += 8)
      if (n0 + ty + i < SEQ && m0 + tx < SEQ)
        tile[ty + i][tx] = inh[(size_t)(n0 + ty + i) * SEQ + m0 + tx];
    __syncthreads();
    for (int i = 0; i < 32; i += 8)
      if (m0 + ty + i < SEQ && n0 + tx < SEQ)
        outh[(size_t)(m0 + ty + i) * SEQ + n0 + tx] = tile[tx][ty + i];
  }
}

// ---------------- GEMM A (QKV): 256x256 tile, r2-verbatim (63.9us, 0 conflicts) ----------------
// 8 waves (2Mx4N, 128x64/wave), 4-slot LDS ring, 1 barrier/K-tile, counted vmcnt.
// MODE 0: C^T-register formulation (mfma(b,a)), bf16 out row-major [M][2304]
// MODE 1: fp32 out[m][768] + bias[n]
template <int MODE>
__global__ __launch_bounds__(512, 2) void gemm256_kernel(const unsigned short* __restrict__ A,
                                                         const unsigned short* __restrict__ Bt,
                                                         const float* __restrict__ bias,
                                                         unsigned short* __restrict__ outB,
                                                         float* __restrict__ outF) {
  constexpr int K = 768;
  constexpr int NT = 24;                               // K-tiles of 32
  __shared__ __align__(16) unsigned short Als[4][8192];   // [slot][256 rows][32 cols]
  __shared__ __align__(16) unsigned short Bls[4][8192];
  const int tid = threadIdx.x;
  const int wid = tid >> 6, lane = tid & 63;
  const int s = lane & 15, q = lane >> 4;
  const int wr = wid >> 2, wc = wid & 3;               // 2x4 wave grid, 128x64 per wave
  const int qx8 = ((q ^ ((s >> 1) & 3)) << 3);         // swizzled 16B slot for frag reads

  const int nbx = gridDim.x;
  const int nb = gridDim.x * gridDim.y;
  int id = blockIdx.y * nbx + blockIdx.x;
  {
    int x = id & 7, lid = id >> 3;
    int per = nb >> 3, big = nb & 7;
    id = (x < big) ? x * (per + 1) + lid
                   : big * (per + 1) + (x - big) * per + lid;
  }
  const int m0 = (id / nbx) * 256;
  const int n0 = (id % nbx) * 256;

  float4v acc[8][4];
#pragma unroll
  for (int i = 0; i < 8; i++)
#pragma unroll
    for (int j = 0; j < 4; j++) acc[i][j] = (float4v){0.f, 0.f, 0.f, 0.f};

  const int srow = tid >> 2;                             // 0..127
  const int scol8 = (((tid & 3) ^ ((srow >> 1) & 3)) << 3);
  const unsigned short* gA = A + (size_t)(m0 + srow) * K + scol8;
  const unsigned short* gB = Bt + (size_t)(n0 + srow) * K + scol8;
  unsigned short* lA0 = &Als[0][0] + wid * 512;
  unsigned short* lB0 = &Bls[0][0] + wid * 512;

  auto stage = [&](int t_) {
    const unsigned short* a = gA + t_ * 32;
    const unsigned short* b = gB + t_ * 32;
    unsigned short* la = lA0 + (t_ & 3) * 8192;
    unsigned short* lb = lB0 + (t_ & 3) * 8192;
    gll16(a, la); gll16(a + 128 * K, la + 4096);
    gll16(b, lb); gll16(b + 128 * K, lb + 4096);
  };

  stage(0); stage(1); stage(2);
  VMW8;            // tile 0 landed (12 outstanding -> 8); tiles 1,2 in flight
  barx();

  const int laneA = (wr * 128 + s) * 32 + qx8;
  const int laneB = (wc * 64 + s) * 32 + qx8;

#pragma unroll 1
  for (int t = 0; t < NT; ++t) {
    const unsigned short* As = &Als[0][0] + (t & 3) * 8192;
    const unsigned short* Bs = &Bls[0][0] + (t & 3) * 8192;
    short8 bfr[4], afr[4], afr2[4];
#pragma unroll
    for (int nj = 0; nj < 4; ++nj) bfr[nj] = *(const short8*)&Bs[laneB + nj * 512];
#pragma unroll
    for (int mi = 0; mi < 4; ++mi) afr[mi]  = *(const short8*)&As[laneA + mi * 512];
#pragma unroll
    for (int mi = 0; mi < 4; ++mi) afr2[mi] = *(const short8*)&As[laneA + (mi + 4) * 512];
    if (t < NT - 3) stage(t + 3);
    __builtin_amdgcn_s_setprio(1);
#pragma unroll
    for (int mi = 0; mi < 4; ++mi)
#pragma unroll
      for (int nj = 0; nj < 4; ++nj) {
        if (MODE == 0)
          acc[mi][nj] = __builtin_amdgcn_mfma_f32_16x16x32_bf16(bfr[nj], afr[mi], acc[mi][nj], 0, 0, 0);
        else
          acc[mi][nj] = __builtin_amdgcn_mfma_f32_16x16x32_bf16(afr[mi], bfr[nj], acc[mi][nj], 0, 0, 0);
      }
#pragma unroll
    for (int mi = 0; mi < 4; ++mi)
#pragma unroll
      for (int nj = 0; nj < 4; ++nj) {
        if (MODE == 0)
          acc[mi + 4][nj] = __builtin_amdgcn_mfma_f32_16x16x32_bf16(bfr[nj], afr2[mi], acc[mi + 4][nj], 0, 0, 0);
        else
          acc[mi + 4][nj] = __builtin_amdgcn_mfma_f32_16x16x32_bf16(afr2[mi], bfr[nj], acc[mi + 4][nj], 0, 0, 0);
      }
    __builtin_amdgcn_s_setprio(0);
    if (t < NT - 3)      { VMW8; }
    else if (t == NT - 3){ VMW4; }
    else if (t == NT - 2){ VMW0; }
    barx();
  }

  if (MODE == 0) {
#pragma unroll
    for (int mi = 0; mi < 8; ++mi) {
      size_t mrow = (size_t)(m0 + wr * 128 + mi * 16 + s) * QKVLD;
#pragma unroll
      for (int nj = 0; nj < 4; ++nj) {
        int n = n0 + wc * 64 + nj * 16 + q * 4;
        ushort4v ov;
        ov.x = f2bf(acc[mi][nj][0]); ov.y = f2bf(acc[mi][nj][1]);
        ov.z = f2bf(acc[mi][nj][2]); ov.w = f2bf(acc[mi][nj][3]);
        *(ushort4v*)&outB[mrow + n] = ov;
      }
    }
  } else {
#pragma unroll
    for (int mi = 0; mi < 8; ++mi) {
      int mbase = m0 + wr * 128 + mi * 16 + q * 4;
#pragma unroll
      for (int nj = 0; nj < 4; ++nj) {
        int ng = n0 + wc * 64 + nj * 16 + s;
        float bv = bias[ng];
#pragma unroll
        for (int r = 0; r < 4; ++r)
          outF[(size_t)(mbase + r) * 768 + ng] = acc[mi][nj][r] + bv;
      }
    }
  }
}

// ---------------- GEMM B (proj): 128x128 tile, high-occupancy (r0 structure + swizzle) ----
// 256 thr (4 waves 2x2, 64x64/wave), 16KB LDS, ~72 VGPR -> 4+ blocks/CU. For the
// proj GEMM the 256^2 grid is only 147 blocks (109 CUs idle); 128^2 gives 588.
// Swizzle chunk^=(row>>1)&3 on both stage-source and frag reads (r2-derivation:
// all row bases are x16 so (row>>1)&3 == (s>>1)&3 / (srow>>1)&3).
template <int MODE>
__global__ __launch_bounds__(256) void gemm128_kernel(const unsigned short* __restrict__ A,
                                                      const unsigned short* __restrict__ Bt,
                                                      const float* __restrict__ bias,
                                                      unsigned short* __restrict__ outB,
                                                      float* __restrict__ outF) {
  constexpr int K = 768;
  __shared__ __align__(16) unsigned short Als[128 * 32];
  __shared__ __align__(16) unsigned short Bls[128 * 32];
  const int tid = threadIdx.x;
  const int wid = tid >> 6, lane = tid & 63;
  const int s = lane & 15, q = lane >> 4;
  const int wr = wid >> 1, wc = wid & 1;           // 2x2 wave grid, 64x64 per wave
  const int qx8 = ((q ^ ((s >> 1) & 3)) << 3);

  const int nbx = gridDim.x;
  const int nb = gridDim.x * gridDim.y;
  int id = blockIdx.y * nbx + blockIdx.x;
  {
    int x = id & 7, lid = id >> 3;
    int per = nb >> 3, big = nb & 7;
    id = (x < big) ? x * (per + 1) + lid
                   : big * (per + 1) + (x - big) * per + lid;
  }
  const int m0 = (id / nbx) * 128;
  const int n0 = (id % nbx) * 128;

  float4v acc[4][4];
#pragma unroll
  for (int i = 0; i < 4; i++)
#pragma unroll
    for (int j = 0; j < 4; j++) acc[i][j] = (float4v){0.f, 0.f, 0.f, 0.f};

  const int srow = lane >> 2;           // 0..15
  const int scol8 = (((lane & 3) ^ ((srow >> 1) & 3)) << 3);

  const unsigned short* ga = A  + (size_t)(m0 + wid * 32 + srow) * K + scol8;
  const unsigned short* gb = Bt + (size_t)(n0 + wid * 32 + srow) * K + scol8;
  unsigned short* la = &Als[wid * 32 * 32];
  unsigned short* lb = &Bls[wid * 32 * 32];

  for (int kt = 0; kt < K; kt += 32) {
    gll16(ga,           la);
    gll16(ga + 16 * K,  la + 16 * 32);
    gll16(gb,           lb);
    gll16(gb + 16 * K,  lb + 16 * 32);
    ga += 32; gb += 32;
    __syncthreads();   // drains vmcnt -> staged data visible

    short8 af[4], bf[4];
#pragma unroll
    for (int i = 0; i < 4; i++)
      af[i] = *(const short8*)&Als[(wr * 64 + i * 16 + s) * 32 + qx8];
#pragma unroll
    for (int j = 0; j < 4; j++)
      bf[j] = *(const short8*)&Bls[(wc * 64 + j * 16 + s) * 32 + qx8];
#pragma unroll
    for (int i = 0; i < 4; i++)
#pragma unroll
      for (int j = 0; j < 4; j++) {
        if (MODE == 0)
          acc[i][j] = __builtin_amdgcn_mfma_f32_16x16x32_bf16(bf[j], af[i], acc[i][j], 0, 0, 0);
        else
          acc[i][j] = __builtin_amdgcn_mfma_f32_16x16x32_bf16(af[i], bf[j], acc[i][j], 0, 0, 0);
      }
    __syncthreads();   // before next overwrite
  }

  if (MODE == 0) {
#pragma unroll
    for (int i = 0; i < 4; i++) {
      size_t mrow = (size_t)(m0 + wr * 64 + i * 16 + s) * QKVLD;
#pragma unroll
      for (int j = 0; j < 4; j++) {
        int n = n0 + wc * 64 + j * 16 + q * 4;
        ushort4v ov;
        ov.x = f2bf(acc[i][j][0]); ov.y = f2bf(acc[i][j][1]);
        ov.z = f2bf(acc[i][j][2]); ov.w = f2bf(acc[i][j][3]);
        *(ushort4v*)&outB[mrow + n] = ov;
      }
    }
  } else {
#pragma unroll
    for (int i = 0; i < 4; i++) {
      int mbase = m0 + wr * 64 + i * 16 + q * 4;
#pragma unroll
      for (int j = 0; j < 4; j++) {
        int ng = n0 + wc * 64 + j * 16 + s;
        float bv = bias[ng];
#pragma unroll
        for (int r = 0; r < 4; r++)
          outF[(size_t)(mbase + r) * 768 + ng] = acc[i][j][r] + bv;
      }
    }
  }
}

// ---------------- attention: one block per (b,h), S^T formulation ----------------
// SCRATCH FIX (rule #20): the old pfrag path did sacc[src] with src = runtime
// select -> whole sacc array spilled to scratch (~224B/thread, ~5x slowdown,
// m214 r286). Now every sacc index is compile-time (unrolled); the tt==12
// validity is handled by selecting the RESULT, and tt==13 is pruned statically.
__global__ __launch_bounds__(256) void attn_kernel(const unsigned short* __restrict__ qkv,
                                                   const float* __restrict__ saT,
                                                   unsigned short* __restrict__ outA) {
  constexpr int WV = 228;   // stride: 114 dwords == 18 mod 32 -> b64 frag reads conflict-free
  __shared__ __align__(16) unsigned short Kl[196 * 64];  // K rows, chunk-swizzled
  __shared__ __align__(16) unsigned short Vt[64 * WV];   // V^T [d][m], m zero-padded to 224
  const int tid = threadIdx.x, wid = tid >> 6, lane = tid & 63;
  const int s = lane & 15, q = lane >> 4;
  const int bh = blockIdx.x;
  const int b = bh / 12, h = bh % 12;
  const unsigned short* Qb = qkv + (size_t)b * SEQ * QKVLD + h * 64;
  const unsigned short* Kb = Qb + 768;
  const unsigned short* Vb = Qb + 1536;

  // stage K: row r, chunk c (16B); LDS chunk = c ^ gK(r); 8 lanes/row -> 128B coalesced
  {
    const int r0 = tid >> 3, c = tid & 7;
    for (int p = 0; p < 7; ++p) {
      int r = p * 32 + r0;
      if (r < 196) {
        short8 v = *(const short8*)&Kb[(size_t)r * QKVLD + c * 8];
        int gk = ((r >> 3) & 3) ^ ((r & 1) << 2);
        *(short8*)&Kl[r * 64 + ((c ^ gk) << 3)] = v;
      }
    }
  }
  // stage V^T: thread covers m = mb*64 + (tid&63), d = d0..d0+15
  {
    const int ms = tid & 63;
    const int d0 = (tid >> 6) * 16;
    for (int mb = 0; mb < 4; ++mb) {
      int m = mb * 64 + ms;
      if (m < 224) {
        if (m < 196) {
          short8 v0 = *(const short8*)&Vb[(size_t)m * QKVLD + d0];
          short8 v1 = *(const short8*)&Vb[(size_t)m * QKVLD + d0 + 8];
#pragma unroll
          for (int j = 0; j < 8; j++) Vt[(d0 + j) * WV + m] = (unsigned short)v0[j];
#pragma unroll
          for (int j = 0; j < 8; j++) Vt[(d0 + 8 + j) * WV + m] = (unsigned short)v1[j];
        } else {
#pragma unroll
          for (int j = 0; j < 16; j++) Vt[(d0 + j) * WV + m] = 0;
        }
      }
    }
  }
  __syncthreads();

  const int pmbase = (s >> 2) * 8 + (s & 3);   // permuted K-row base for A-frag row s
  const float* saTh = saT + (size_t)h * SEQ * SEQ;

  for (int qt = wid; qt < 13; qt += 4) {
    const int n0 = qt * 16;
    const int nq = n0 + s;
    const int nql = nq > 195 ? 195 : nq;
    short8 qf0 = *(const short8*)&Qb[(size_t)nql * QKVLD + q * 8];
    short8 qf1 = *(const short8*)&Qb[(size_t)nql * QKVLD + 32 + q * 8];

    // S^T tiles: tt = 0..12 (tile tt=13 is entirely m>=196 -> statically skipped)
    float4v sacc[13];
#pragma unroll
    for (int tt = 0; tt < 13; tt++) {
      int t = tt >> 1, h4 = tt & 1;
      int m = t * 32 + h4 * 4 + pmbase;
      if (m > 195) m = 195;                       // garbage rows, masked later
      int gk = ((m >> 3) & 3) ^ ((m & 1) << 2);
      short8 kf0 = *(const short8*)&Kl[m * 64 + ((q ^ gk) << 3)];
      short8 kf1 = *(const short8*)&Kl[m * 64 + (((4 + q) ^ gk) << 3)];
      float4v z = (float4v){0.f, 0.f, 0.f, 0.f};
      z = __builtin_amdgcn_mfma_f32_16x16x32_bf16(kf0, qf0, z, 0, 0, 0);
      z = __builtin_amdgcn_mfma_f32_16x16x32_bf16(kf1, qf1, z, 0, 0, 0);
      sacc[tt] = z;
    }

    // column softmax: lane owns column n. Valid m: tt<12 all; tt==12 only q==0.
    float mx = -3.0e38f;
#pragma unroll
    for (int tt = 0; tt < 12; tt++)
#pragma unroll
      for (int i = 0; i < 4; i++) mx = fmaxf(mx, sacc[tt][i]);
    if (q == 0)
#pragma unroll
      for (int i = 0; i < 4; i++) mx = fmaxf(mx, sacc[12][i]);
    mx = fmaxf(mx, __shfl_xor(mx, 16));
    mx = fmaxf(mx, __shfl_xor(mx, 32));
    const float CE = SCALE * 1.44269504f;
    float sm = 0.f;
#pragma unroll
    for (int tt = 0; tt < 12; tt++)
#pragma unroll
      for (int i = 0; i < 4; i++) {
        float e = __builtin_amdgcn_exp2f((sacc[tt][i] - mx) * CE);
        sacc[tt][i] = e; sm += e;
      }
    if (q == 0) {
#pragma unroll
      for (int i = 0; i < 4; i++) {
        float e = __builtin_amdgcn_exp2f((sacc[12][i] - mx) * CE);
        sacc[12][i] = e; sm += e;
      }
    }
    sm += __shfl_xor(sm, 16);
    sm += __shfl_xor(sm, 32);
    const float inv = 1.0f / sm;

    // P^T fragments: pfrag[t][j] = P^T[m = t*32 + q*8 + j][n], j = h4*4 + i
    // All sacc indices compile-time; validity applied to the RESULT (no src idx).
    short8 pfrag[7];
#pragma unroll
    for (int t = 0; t < 7; t++) {
      short8 pf;
#pragma unroll
      for (int h4 = 0; h4 < 2; h4++) {
        const int tt = 2 * t + h4;
        float pv0 = 0.f, pv1 = 0.f, pv2 = 0.f, pv3 = 0.f;
        if (tt < 13) {                              // compile-time prune of tt==13
          bool valid = (tt < 12) || (q == 0);
          float a0 = 0.f, a1 = 0.f, a2 = 0.f, a3 = 0.f;
          if (valid) {
            const float* sp = saTh + (size_t)(t * 32 + q * 8 + h4 * 4) * SEQ + nql;
            a0 = sp[0]; a1 = sp[SEQ]; a2 = sp[2 * SEQ]; a3 = sp[3 * SEQ];
          }
          pv0 = valid ? (sacc[tt][0] * inv + a0) : 0.f;
          pv1 = valid ? (sacc[tt][1] * inv + a1) : 0.f;
          pv2 = valid ? (sacc[tt][2] * inv + a2) : 0.f;
          pv3 = valid ? (sacc[tt][3] * inv + a3) : 0.f;
        }
        pf[h4 * 4 + 0] = (short)f2bf(pv0);
        pf[h4 * 4 + 1] = (short)f2bf(pv1);
        pf[h4 * 4 + 2] = (short)f2bf(pv2);
        pf[h4 * 4 + 3] = (short)f2bf(pv3);
      }
      pfrag[t] = pf;
    }

    // O^T = V^T . P^T : A-frag = V^T rows (from LDS, two b64 reads), B-frag = pfrag
#pragma unroll
    for (int dt = 0; dt < 4; dt++) {
      float4v o = (float4v){0.f, 0.f, 0.f, 0.f};
#pragma unroll
      for (int t = 0; t < 7; t++) {
        const unsigned short* vp = &Vt[(dt * 16 + s) * WV + t * 32 + q * 8];
        short4v v0 = *(const short4v*)vp;
        short4v v1 = *(const short4v*)(vp + 4);
        short8 vf;
        vf[0] = v0[0]; vf[1] = v0[1]; vf[2] = v0[2]; vf[3] = v0[3];
        vf[4] = v1[0]; vf[5] = v1[1]; vf[6] = v1[2]; vf[7] = v1[3];
        o = __builtin_amdgcn_mfma_f32_16x16x32_bf16(vf, pfrag[t], o, 0, 0, 0);
      }
      // lane holds O^T[d = dt*16 + q*4 + r][n = nq]
      if (nq < 196) {
        ushort4v ov;
        ov.x = f2bf(o[0]); ov.y = f2bf(o[1]); ov.z = f2bf(o[2]); ov.w = f2bf(o[3]);
        *(ushort4v*)&outA[((size_t)b * SEQ + nq) * DIM + h * 64 + dt * 16 + q * 4] = ov;
      }
    }
  }
}

extern "C" void kernel_launch(void* const* d_in, const int* in_sizes, int n_in,
                              void* d_out, int out_size, void* d_ws, size_t ws_size,
                              hipStream_t stream) {
  const float* x        = (const float*)d_in[0];
  const float* Wqkv     = (const float*)d_in[1];
  const float* static_a = (const float*)d_in[2];
  const float* Wproj    = (const float*)d_in[3];
  const float* bproj    = (const float*)d_in[4];
  float* out = (float*)d_out;

  unsigned char* ws = (unsigned char*)d_ws;
  size_t off = 0;
  unsigned short* qkv_ws = (unsigned short*)(ws + off); off += (size_t)NTOK * QKVLD * 2;   // 57.8 MB
  unsigned short* xa_ws  = (unsigned short*)(ws + off); off += (size_t)NTOK * DIM * 2;     // x_bf16, reused as attn-out
  unsigned short* wqkvt  = (unsigned short*)(ws + off); off += (size_t)3 * DIM * DIM * 2;  // W_qkv^T bf16
  unsigned short* wprojt = (unsigned short*)(ws + off); off += (size_t)DIM * DIM * 2;      // W_proj^T bf16
  float* saT_ws          = (float*)(ws + off);          off += (size_t)HEADS * SEQ * SEQ * 4; // 1.84 MB

  prep_kernel<<<PREP_NB, 256, 0, stream>>>(x, Wqkv, Wproj, static_a,
                                           xa_ws, wqkvt, wprojt, saT_ws);
  gemm256_kernel<0><<<dim3(3 * DIM / 256, NTOK / 256), 512, 0, stream>>>(xa_ws, wqkvt, nullptr, qkv_ws, nullptr);
  attn_kernel<<<BATCH * HEADS, 256, 0, stream>>>(qkv_ws, saT_ws, xa_ws);
  gemm128_kernel<1><<<dim3(DIM / 128, NTOK / 128), 256, 0, stream>>>(xa_ws, wprojt, bproj, nullptr, out);
}